// Round 11
// baseline (91.311 us; speedup 1.0000x reference)
//
#include <hip/hip_runtime.h>
#include <hip/hip_fp16.h>

#define OUT_UNITS 128

// ---------------- Kernel 0: fused prep -------------------------------------
// job A (i < n4):  w fp32 -> fp16 into workspace (float4 -> 4 halves)
// job B (i < nnz): CSR row pointers from sorted COO rows
__global__ void prep(const float4* __restrict__ w4, uint2* __restrict__ wh, int n4,
                     const int* __restrict__ rows, int* __restrict__ row_start,
                     int nnz, int n_rows) {
    int i = blockIdx.x * blockDim.x + threadIdx.x;
    if (i < n4) {
        float4 f = w4[i];
        __half2 h01 = __floats2half2_rn(f.x, f.y);
        __half2 h23 = __floats2half2_rn(f.z, f.w);
        wh[i] = make_uint2(*(unsigned*)&h01, *(unsigned*)&h23);
    }
    if (i < nnz) {
        int cur = rows[i];
        if (i == 0) {
            for (int r = 0; r <= cur; ++r) row_start[r] = 0;
        } else {
            int prev = rows[i - 1];
            for (int r = prev + 1; r <= cur; ++r) row_start[r] = i;
        }
        if (i == nnz - 1) {
            for (int r = cur + 1; r <= n_rows; ++r) row_start[r] = nnz;
        }
    }
}

// ---------------- Kernel 1: 4 waves/block, one row per wave ------------------
// One nnz = one wave instruction: the 256B fp16 w-row is read as 64 lanes x
// 4B (half2 per lane). (c,v) is wave-uniform -> LDS read is a same-address
// broadcast (free, non-convergent). Each lane owns output cols {2*lane,
// 2*lane+1} for the whole row: no cross-lane folds, coalesced float2 write.
// Per nnz: 1 ds_read_b64 + addr + 1 global_load_dword + 2 v_fma_mix_f32
// (~6 wave-instrs vs ~12 in round 10's quad scheme). v stays fp32 ->
// numerics identical to round 10 (absmax 0.25).
__global__ __launch_bounds__(256, 4)
void spmm_row_wave(const float* __restrict__ vals,
                   const __half* __restrict__ wh,
                   const int* __restrict__ cols,
                   const int* __restrict__ row_start,
                   float* __restrict__ out,
                   int n_rows) {
    __shared__ int2 cvbuf[4][64];

    const int wave = __builtin_amdgcn_readfirstlane((int)(threadIdx.x >> 6));
    const int lane = threadIdx.x & 63;
    const int r    = blockIdx.x * 4 + wave;
    if (r >= n_rows) return;

    const int start = row_start[r];
    const int end   = row_start[r + 1];
    const char* __restrict__ whb = (const char*)wh;
    const int loff = lane << 2;          // lane*4 B: 64 lanes = 256B = one row
    int2* cv = cvbuf[wave];

    float2 acc = make_float2(0.f, 0.f);  // cols 2*lane, 2*lane+1

    for (int base = start; base < end; base += 64) {
        const int navail = min(64, end - base);
        // stage (c, v): pad lanes get (valid col, v=0) so reads to 63 are safe
        const int idx = base + min(lane, navail - 1);
        int   c_l = cols[idx];
        float v_l = (lane < navail) ? vals[idx] : 0.f;
        cv[lane] = make_int2(c_l, __float_as_int(v_l));
        // same-wave LDS: program-ordered, no barrier

        const int n4 = (navail + 3) & ~3;  // <= 64; pads have v=0

        for (int t = 0; t < n4; t += 4) {
            // ---- 4 broadcast LDS reads (uniform addr -> free broadcast) ----
            int2 p0 = cv[t + 0];
            int2 p1 = cv[t + 1];
            int2 p2 = cv[t + 2];
            int2 p3 = cv[t + 3];
            // ---- 4 independent 256B row loads (1 dword/lane each) ----
            unsigned q0 = *(const unsigned*)(whb + (((size_t)(unsigned)p0.x) << 8) + loff);
            unsigned q1 = *(const unsigned*)(whb + (((size_t)(unsigned)p1.x) << 8) + loff);
            unsigned q2 = *(const unsigned*)(whb + (((size_t)(unsigned)p2.x) << 8) + loff);
            unsigned q3 = *(const unsigned*)(whb + (((size_t)(unsigned)p3.x) << 8) + loff);
            // ---- consume: 2 v_fma_mix_f32 per nnz ----
            __half2 h0 = *(__half2*)&q0;
            __half2 h1 = *(__half2*)&q1;
            __half2 h2 = *(__half2*)&q2;
            __half2 h3 = *(__half2*)&q3;
            float v0 = __int_as_float(p0.y);
            float v1 = __int_as_float(p1.y);
            float v2 = __int_as_float(p2.y);
            float v3 = __int_as_float(p3.y);
            acc.x = fmaf(v0, __half2float(h0.x), acc.x);
            acc.y = fmaf(v0, __half2float(h0.y), acc.y);
            acc.x = fmaf(v1, __half2float(h1.x), acc.x);
            acc.y = fmaf(v1, __half2float(h1.y), acc.y);
            acc.x = fmaf(v2, __half2float(h2.x), acc.x);
            acc.y = fmaf(v2, __half2float(h2.y), acc.y);
            acc.x = fmaf(v3, __half2float(h3.x), acc.x);
            acc.y = fmaf(v3, __half2float(h3.y), acc.y);
        }
    }

    ((float2*)(out + (size_t)r * OUT_UNITS))[lane] = acc;
}

extern "C" void kernel_launch(void* const* d_in, const int* in_sizes, int n_in,
                              void* d_out, int out_size, void* d_ws, size_t ws_size,
                              hipStream_t stream) {
    const float* vals = (const float*)d_in[0];
    const float* w    = (const float*)d_in[1];
    const int*   rows = (const int*)d_in[2];
    const int*   cols = (const int*)d_in[3];
    float* out = (float*)d_out;

    const int nnz    = in_sizes[0];
    const int n_rows = out_size / OUT_UNITS;  // 16384
    const int w_n    = in_sizes[1];           // 8192*128 = 1048576
    const int n4     = w_n / 4;

    // ws layout: [0, 64KB+4) row_start ; [128KB, 128KB+2MB) w fp16
    int*    row_start = (int*)d_ws;
    __half* wh        = (__half*)((char*)d_ws + (128 << 10));

    const int prep_threads = (nnz > n4) ? nnz : n4;
    prep<<<(prep_threads + 255) / 256, 256, 0, stream>>>(
        (const float4*)w, (uint2*)wh, n4, rows, row_start, nnz, n_rows);
    spmm_row_wave<<<(n_rows + 3) / 4, 256, 0, stream>>>(vals, wh, cols, row_start, out, n_rows);
}

// Round 13
// 87.862 us; speedup vs baseline: 1.0393x; 1.0393x over previous
//
#include <hip/hip_runtime.h>
#include <hip/hip_fp16.h>

#define OUT_UNITS 128

// ---------------- Kernel 0: fused prep -------------------------------------
// job A (i < n4):  w fp32 -> fp16 into workspace (float4 -> 4 halves)
// job B (i < nnz): CSR row pointers from sorted COO rows
__global__ void prep(const float4* __restrict__ w4, uint2* __restrict__ wh, int n4,
                     const int* __restrict__ rows, int* __restrict__ row_start,
                     int nnz, int n_rows) {
    int i = blockIdx.x * blockDim.x + threadIdx.x;
    if (i < n4) {
        float4 f = w4[i];
        __half2 h01 = __floats2half2_rn(f.x, f.y);
        __half2 h23 = __floats2half2_rn(f.z, f.w);
        wh[i] = make_uint2(*(unsigned*)&h01, *(unsigned*)&h23);
    }
    if (i < nnz) {
        int cur = rows[i];
        if (i == 0) {
            for (int r = 0; r <= cur; ++r) row_start[r] = 0;
        } else {
            int prev = rows[i - 1];
            for (int r = prev + 1; r <= cur; ++r) row_start[r] = i;
        }
        if (i == nnz - 1) {
            for (int r = cur + 1; r <= n_rows; ++r) row_start[r] = nnz;
        }
    }
}

// ---------------- Kernel 1: 4 waves/block, one row per wave ------------------
// Round 10 structure (fp16 w, quarter-wave split: 16 lanes x 16B cover one
// 256B row, one dwordx4 instr serves 4 nnz) + round 9's 2-stage software
// pipeline: stage B's ds_reads+gathers issue BEFORE consuming stage A, so
// 8 x 1KB gathers stay in flight per wave (8 KB vs round 10's 4 KB).
// (c,v) broadcast via per-wave LDS (non-convergent ds_read — the round-8
// win; readlane is convergent and pins MLP to 1). Pads get v=0; all 64 LDS
// entries written every chunk so pipelined pad reads are safe.
__global__ __launch_bounds__(256, 4)
void spmm_row_wave(const float* __restrict__ vals,
                   const __half* __restrict__ wh,
                   const int* __restrict__ cols,
                   const int* __restrict__ row_start,
                   float* __restrict__ out,
                   int n_rows) {
    __shared__ int2 cvbuf[4][64];

    const int wave = __builtin_amdgcn_readfirstlane((int)(threadIdx.x >> 6));
    const int lane = threadIdx.x & 63;
    const int r    = blockIdx.x * 4 + wave;
    if (r >= n_rows) return;

    const int start   = row_start[r];
    const int end     = row_start[r + 1];
    const int quarter = lane >> 4;   // which nnz of the quad
    const int sub     = lane & 15;   // 16 lanes x 8 halves = 128 cols
    const char* __restrict__ whb = (const char*)wh;
    const int loff = sub << 4;       // sub*16 bytes
    int2* cv = cvbuf[wave];

    float4 accA = make_float4(0.f, 0.f, 0.f, 0.f);  // cols sub*8 + 0..3
    float4 accB = make_float4(0.f, 0.f, 0.f, 0.f);  // cols sub*8 + 4..7

    for (int base = start; base < end; base += 64) {
        const int navail = min(64, end - base);
        // stage (c, v): pad lanes get (valid col, v=0)
        const int idx = base + min(lane, navail - 1);
        int   c_l = cols[idx];
        float v_l = (lane < navail) ? vals[idx] : 0.f;
        cv[lane] = make_int2(c_l, __float_as_int(v_l));
        // same-wave LDS: program-ordered, no barrier

        const int nquad  = (navail + 3) >> 2;
        const int nquad4 = (nquad + 3) & ~3;   // 4..16, multiple of 4

        // ---- prologue: stage A = quads [0,4) ----
        int2  pA[4];
        uint4 qA[4];
#pragma unroll
        for (int j = 0; j < 4; ++j) pA[j] = cv[4 * j + quarter];
#pragma unroll
        for (int j = 0; j < 4; ++j)
            qA[j] = *(const uint4*)(whb + (((size_t)(unsigned)pA[j].x) << 8) + loff);

        for (int t = 4; t < nquad4; t += 4) {
            // ---- issue stage B before consuming A ----
            int2  pB[4];
            uint4 qB[4];
#pragma unroll
            for (int j = 0; j < 4; ++j) pB[j] = cv[4 * (t + j) + quarter];
#pragma unroll
            for (int j = 0; j < 4; ++j)
                qB[j] = *(const uint4*)(whb + (((size_t)(unsigned)pB[j].x) << 8) + loff);
            // ---- consume stage A (waits vmcnt(4): B stays in flight) ----
#pragma unroll
            for (int j = 0; j < 4; ++j) {
                float v = __int_as_float(pA[j].y);
                const __half2* h = (const __half2*)&qA[j];
                float2 f0 = __half22float2(h[0]);
                float2 f1 = __half22float2(h[1]);
                float2 f2 = __half22float2(h[2]);
                float2 f3 = __half22float2(h[3]);
                accA.x = fmaf(v, f0.x, accA.x); accA.y = fmaf(v, f0.y, accA.y);
                accA.z = fmaf(v, f1.x, accA.z); accA.w = fmaf(v, f1.y, accA.w);
                accB.x = fmaf(v, f2.x, accB.x); accB.y = fmaf(v, f2.y, accB.y);
                accB.z = fmaf(v, f3.x, accB.z); accB.w = fmaf(v, f3.y, accB.w);
            }
            // ---- rotate B -> A ----
#pragma unroll
            for (int j = 0; j < 4; ++j) { pA[j] = pB[j]; qA[j] = qB[j]; }
        }

        // ---- epilogue: consume final stage ----
#pragma unroll
        for (int j = 0; j < 4; ++j) {
            float v = __int_as_float(pA[j].y);
            const __half2* h = (const __half2*)&qA[j];
            float2 f0 = __half22float2(h[0]);
            float2 f1 = __half22float2(h[1]);
            float2 f2 = __half22float2(h[2]);
            float2 f3 = __half22float2(h[3]);
            accA.x = fmaf(v, f0.x, accA.x); accA.y = fmaf(v, f0.y, accA.y);
            accA.z = fmaf(v, f1.x, accA.z); accA.w = fmaf(v, f1.y, accA.w);
            accB.x = fmaf(v, f2.x, accB.x); accB.y = fmaf(v, f2.y, accB.y);
            accB.z = fmaf(v, f3.x, accB.z); accB.w = fmaf(v, f3.y, accB.w);
        }
    }

    // fold the 4 quarters (disjoint nnz subsets)
#pragma unroll
    for (int d = 16; d <= 32; d <<= 1) {
        accA.x += __shfl_xor(accA.x, d); accA.y += __shfl_xor(accA.y, d);
        accA.z += __shfl_xor(accA.z, d); accA.w += __shfl_xor(accA.w, d);
        accB.x += __shfl_xor(accB.x, d); accB.y += __shfl_xor(accB.y, d);
        accB.z += __shfl_xor(accB.z, d); accB.w += __shfl_xor(accB.w, d);
    }

    if (quarter == 0) {
        float4* o = (float4*)(out + (size_t)r * OUT_UNITS + sub * 8);
        o[0] = accA;
        o[1] = accB;
    }
}

extern "C" void kernel_launch(void* const* d_in, const int* in_sizes, int n_in,
                              void* d_out, int out_size, void* d_ws, size_t ws_size,
                              hipStream_t stream) {
    const float* vals = (const float*)d_in[0];
    const float* w    = (const float*)d_in[1];
    const int*   rows = (const int*)d_in[2];
    const int*   cols = (const int*)d_in[3];
    float* out = (float*)d_out;

    const int nnz    = in_sizes[0];
    const int n_rows = out_size / OUT_UNITS;  // 16384
    const int w_n    = in_sizes[1];           // 8192*128 = 1048576
    const int n4     = w_n / 4;

    // ws layout: [0, 64KB+4) row_start ; [128KB, 128KB+2MB) w fp16
    int*    row_start = (int*)d_ws;
    __half* wh        = (__half*)((char*)d_ws + (128 << 10));

    const int prep_threads = (nnz > n4) ? nnz : n4;
    prep<<<(prep_threads + 255) / 256, 256, 0, stream>>>(
        (const float4*)w, (uint2*)wh, n4, rows, row_start, nnz, n_rows);
    spmm_row_wave<<<(n_rows + 3) / 4, 256, 0, stream>>>(vals, wh, cols, row_start, out, n_rows);
}

// Round 14
// 87.585 us; speedup vs baseline: 1.0425x; 1.0032x over previous
//
#include <hip/hip_runtime.h>
#include <hip/hip_fp16.h>

#define OUT_UNITS 128
#define ROWS_PER_BLOCK 8   // 512 threads = 8 waves, one row per wave

// ---------------- Kernel 0: fused prep -------------------------------------
// job A (i < n4):  w fp32 -> fp16 into workspace (float4 -> 4 halves)
// job B (i < nnz): CSR row pointers from sorted COO rows
__global__ void prep(const float4* __restrict__ w4, uint2* __restrict__ wh, int n4,
                     const int* __restrict__ rows, int* __restrict__ row_start,
                     int nnz, int n_rows) {
    int i = blockIdx.x * blockDim.x + threadIdx.x;
    if (i < n4) {
        float4 f = w4[i];
        __half2 h01 = __floats2half2_rn(f.x, f.y);
        __half2 h23 = __floats2half2_rn(f.z, f.w);
        wh[i] = make_uint2(*(unsigned*)&h01, *(unsigned*)&h23);
    }
    if (i < nnz) {
        int cur = rows[i];
        if (i == 0) {
            for (int r = 0; r <= cur; ++r) row_start[r] = 0;
        } else {
            int prev = rows[i - 1];
            for (int r = prev + 1; r <= cur; ++r) row_start[r] = i;
        }
        if (i == nnz - 1) {
            for (int r = cur + 1; r <= n_rows; ++r) row_start[r] = nnz;
        }
    }
}

// ---------------- Kernel 1: 8 waves/block, one row per wave ------------------
// Round 13 structure (fp16 w, quarter-wave split: 16 lanes x 16B cover one
// 256B row, one dwordx4 instr serves 4 nnz; 2-stage pipeline keeps 8 x 1KB
// gathers in flight) with 512-thread blocks: rounds 3-13 pinned occupancy
// at ~20/32 waves (workgroup-slot cap at 256-thread blocks). 8 waves/block
// + __launch_bounds__(512, 8) targets 32 waves/CU -> ~1.6x outstanding
// gather bytes per CU. (c,v) broadcast via per-wave LDS (non-convergent
// ds_read; readlane is convergent and pinned MLP to 1 in rounds 4-7).
__global__ __launch_bounds__(512, 8)
void spmm_row_wave(const float* __restrict__ vals,
                   const __half* __restrict__ wh,
                   const int* __restrict__ cols,
                   const int* __restrict__ row_start,
                   float* __restrict__ out,
                   int n_rows) {
    __shared__ int2 cvbuf[ROWS_PER_BLOCK][64];

    const int wave = __builtin_amdgcn_readfirstlane((int)(threadIdx.x >> 6));
    const int lane = threadIdx.x & 63;
    const int r    = blockIdx.x * ROWS_PER_BLOCK + wave;
    if (r >= n_rows) return;

    const int start   = row_start[r];
    const int end     = row_start[r + 1];
    const int quarter = lane >> 4;   // which nnz of the quad
    const int sub     = lane & 15;   // 16 lanes x 8 halves = 128 cols
    const char* __restrict__ whb = (const char*)wh;
    const int loff = sub << 4;       // sub*16 bytes
    int2* cv = cvbuf[wave];

    float4 accA = make_float4(0.f, 0.f, 0.f, 0.f);  // cols sub*8 + 0..3
    float4 accB = make_float4(0.f, 0.f, 0.f, 0.f);  // cols sub*8 + 4..7

    for (int base = start; base < end; base += 64) {
        const int navail = min(64, end - base);
        // stage (c, v): pad lanes get (valid col, v=0)
        const int idx = base + min(lane, navail - 1);
        int   c_l = cols[idx];
        float v_l = (lane < navail) ? vals[idx] : 0.f;
        cv[lane] = make_int2(c_l, __float_as_int(v_l));
        // same-wave LDS: program-ordered, no barrier

        const int nquad  = (navail + 3) >> 2;
        const int nquad4 = (nquad + 3) & ~3;   // 4..16, multiple of 4

        // ---- prologue: stage A = quads [0,4) ----
        int2  pA[4];
        uint4 qA[4];
#pragma unroll
        for (int j = 0; j < 4; ++j) pA[j] = cv[4 * j + quarter];
#pragma unroll
        for (int j = 0; j < 4; ++j)
            qA[j] = *(const uint4*)(whb + (((size_t)(unsigned)pA[j].x) << 8) + loff);

        for (int t = 4; t < nquad4; t += 4) {
            // ---- issue stage B before consuming A ----
            int2  pB[4];
            uint4 qB[4];
#pragma unroll
            for (int j = 0; j < 4; ++j) pB[j] = cv[4 * (t + j) + quarter];
#pragma unroll
            for (int j = 0; j < 4; ++j)
                qB[j] = *(const uint4*)(whb + (((size_t)(unsigned)pB[j].x) << 8) + loff);
            // ---- consume stage A (waits vmcnt(4): B stays in flight) ----
#pragma unroll
            for (int j = 0; j < 4; ++j) {
                float v = __int_as_float(pA[j].y);
                const __half2* h = (const __half2*)&qA[j];
                float2 f0 = __half22float2(h[0]);
                float2 f1 = __half22float2(h[1]);
                float2 f2 = __half22float2(h[2]);
                float2 f3 = __half22float2(h[3]);
                accA.x = fmaf(v, f0.x, accA.x); accA.y = fmaf(v, f0.y, accA.y);
                accA.z = fmaf(v, f1.x, accA.z); accA.w = fmaf(v, f1.y, accA.w);
                accB.x = fmaf(v, f2.x, accB.x); accB.y = fmaf(v, f2.y, accB.y);
                accB.z = fmaf(v, f3.x, accB.z); accB.w = fmaf(v, f3.y, accB.w);
            }
            // ---- rotate B -> A ----
#pragma unroll
            for (int j = 0; j < 4; ++j) { pA[j] = pB[j]; qA[j] = qB[j]; }
        }

        // ---- epilogue: consume final stage ----
#pragma unroll
        for (int j = 0; j < 4; ++j) {
            float v = __int_as_float(pA[j].y);
            const __half2* h = (const __half2*)&qA[j];
            float2 f0 = __half22float2(h[0]);
            float2 f1 = __half22float2(h[1]);
            float2 f2 = __half22float2(h[2]);
            float2 f3 = __half22float2(h[3]);
            accA.x = fmaf(v, f0.x, accA.x); accA.y = fmaf(v, f0.y, accA.y);
            accA.z = fmaf(v, f1.x, accA.z); accA.w = fmaf(v, f1.y, accA.w);
            accB.x = fmaf(v, f2.x, accB.x); accB.y = fmaf(v, f2.y, accB.y);
            accB.z = fmaf(v, f3.x, accB.z); accB.w = fmaf(v, f3.y, accB.w);
        }
    }

    // fold the 4 quarters (disjoint nnz subsets)
#pragma unroll
    for (int d = 16; d <= 32; d <<= 1) {
        accA.x += __shfl_xor(accA.x, d); accA.y += __shfl_xor(accA.y, d);
        accA.z += __shfl_xor(accA.z, d); accA.w += __shfl_xor(accA.w, d);
        accB.x += __shfl_xor(accB.x, d); accB.y += __shfl_xor(accB.y, d);
        accB.z += __shfl_xor(accB.z, d); accB.w += __shfl_xor(accB.w, d);
    }

    if (quarter == 0) {
        float4* o = (float4*)(out + (size_t)r * OUT_UNITS + sub * 8);
        o[0] = accA;
        o[1] = accB;
    }
}

extern "C" void kernel_launch(void* const* d_in, const int* in_sizes, int n_in,
                              void* d_out, int out_size, void* d_ws, size_t ws_size,
                              hipStream_t stream) {
    const float* vals = (const float*)d_in[0];
    const float* w    = (const float*)d_in[1];
    const int*   rows = (const int*)d_in[2];
    const int*   cols = (const int*)d_in[3];
    float* out = (float*)d_out;

    const int nnz    = in_sizes[0];
    const int n_rows = out_size / OUT_UNITS;  // 16384
    const int w_n    = in_sizes[1];           // 8192*128 = 1048576
    const int n4     = w_n / 4;

    // ws layout: [0, 64KB+4) row_start ; [128KB, 128KB+2MB) w fp16
    int*    row_start = (int*)d_ws;
    __half* wh        = (__half*)((char*)d_ws + (128 << 10));

    const int prep_threads = (nnz > n4) ? nnz : n4;
    prep<<<(prep_threads + 255) / 256, 256, 0, stream>>>(
        (const float4*)w, (uint2*)wh, n4, rows, row_start, nnz, n_rows);
    spmm_row_wave<<<(n_rows + ROWS_PER_BLOCK - 1) / ROWS_PER_BLOCK, 512, 0, stream>>>(
        vals, wh, cols, row_start, out, n_rows);
}